// Round 7
// baseline (356.301 us; speedup 1.0000x reference)
//
#include <hip/hip_runtime.h>
#include <math.h>

// Problem: S=4096, D=512, H=8, KVH=4, DH=64, M=64, K=8 (B=1)
// ARITHMETIC CONTRACT (frozen, round 5 green): selection-critical path
// emulates numpy-f32 op-for-op:
//  - QKV gemm: per output, sequential f32 fmaf chain in k-ascending order,
//    KC=384 panel split, final __fadd_rn(acc1, acc2)
//  - k1/k2 sums: sequential f32 adds in axis order
//  - stage-1 scores: sequential fmaf chain over d (0..31)
//  - stage-2 einsum: sequential f32 mul+add (NOT fma) over d (0..63)
//  - tables: correctly-rounded f32 (f64 then round)
//  - softmax: *0.125, fl32(exp64), pairwise-8 sum, f32 div
//  - top-k: descending, ties -> lower index
// Round 6: wave-parallel attention (1 wave per (h,s)), same op sequences.

// Workspace (floats)
static constexpr size_t OFF_QKV = 0;              // 4096*1024
static constexpr size_t OFF_Q   = 4194304;        // 8*4096*64   q[h][s][d]
static constexpr size_t OFF_K   = 6291456;        // 4*4096*64   k[kvh][s][d]
static constexpr size_t OFF_V   = 7340032;        // 4*4096*64   v[kvh][s][d]
static constexpr size_t OFF_COS = 8388608;        // 4096*32
static constexpr size_t OFF_SIN = 8519680;        // 4096*32
static constexpr size_t OFF_K1  = 8650752;        // 4*64*32     k1[kvh][r][d]
static constexpr size_t OFF_K2  = 8658944;        // 4*64*32     k2[kvh][c][d]
static constexpr size_t OFF_O   = 8667136;        // 4096*512
static constexpr size_t OFF_W   = 10764288;       // 1024*512

#define LDT 68   // GEMM LDS pad
#define LKP 33   // attn k-row LDS pad (stride 33 -> bank (r+d)%32)

__global__ __launch_bounds__(256) void freq_table_kernel(float* __restrict__ cosT,
    float* __restrict__ sinT) {
  int idx = blockIdx.x * 256 + threadIdx.x;   // 0..131071
  int s = idx >> 5;
  int dp = idx & 31;
  double e = (double)dp * (1.0 / 32.0);
  float pf = (float)pow(10000.0, e);
  float invf = 1.0f / pf;
  float argf = __fmul_rn((float)s, invf);
  cosT[idx] = (float)cos((double)argf);
  sinT[idx] = (float)sin((double)argf);
}

// Tiled NT gemm, chain-order-preserving, KC split via template.
template <int SPLIT>
__global__ __launch_bounds__(256) void gemm_nt_chain(const float* __restrict__ A,
    const float* __restrict__ B, float* __restrict__ C, int N) {
  __shared__ float As[16 * LDT];
  __shared__ float Bs[16 * LDT];
  const int tid = threadIdx.x;
  const int ty = tid >> 4;
  const int tx = tid & 15;
  const int bm = blockIdx.y, bn = blockIdx.x;
  const int lrow = tid >> 2;
  const int lk = (tid & 3) << 2;
  const float* Ap = A + (size_t)(bm * 64 + lrow) * 512 + lk;
  const float* Bp = B + (size_t)(bn * 64 + lrow) * 512 + lk;
  float acc1[4][4] = {{0.f}};
  float acc2[4][4] = {{0.f}};
  for (int kt = 0; kt < 512; kt += 16) {
    float4 av = *(const float4*)(Ap + kt);
    float4 bv = *(const float4*)(Bp + kt);
    __syncthreads();
    As[(lk + 0) * LDT + lrow] = av.x;
    As[(lk + 1) * LDT + lrow] = av.y;
    As[(lk + 2) * LDT + lrow] = av.z;
    As[(lk + 3) * LDT + lrow] = av.w;
    Bs[(lk + 0) * LDT + lrow] = bv.x;
    Bs[(lk + 1) * LDT + lrow] = bv.y;
    Bs[(lk + 2) * LDT + lrow] = bv.z;
    Bs[(lk + 3) * LDT + lrow] = bv.w;
    __syncthreads();
    if (SPLIT != 0 && kt >= SPLIT) {
      #pragma unroll
      for (int k = 0; k < 16; ++k) {
        float4 a4 = *(const float4*)(&As[k * LDT + (ty << 2)]);
        float4 b4 = *(const float4*)(&Bs[k * LDT + (tx << 2)]);
        float af[4] = {a4.x, a4.y, a4.z, a4.w};
        float bf[4] = {b4.x, b4.y, b4.z, b4.w};
        #pragma unroll
        for (int i2 = 0; i2 < 4; ++i2)
          #pragma unroll
          for (int j2 = 0; j2 < 4; ++j2)
            acc2[i2][j2] = fmaf(af[i2], bf[j2], acc2[i2][j2]);
      }
    } else {
      #pragma unroll
      for (int k = 0; k < 16; ++k) {
        float4 a4 = *(const float4*)(&As[k * LDT + (ty << 2)]);
        float4 b4 = *(const float4*)(&Bs[k * LDT + (tx << 2)]);
        float af[4] = {a4.x, a4.y, a4.z, a4.w};
        float bf[4] = {b4.x, b4.y, b4.z, b4.w};
        #pragma unroll
        for (int i2 = 0; i2 < 4; ++i2)
          #pragma unroll
          for (int j2 = 0; j2 < 4; ++j2)
            acc1[i2][j2] = fmaf(af[i2], bf[j2], acc1[i2][j2]);
      }
    }
  }
  float* Cp = C + (size_t)(bm * 64 + (ty << 2)) * N + bn * 64 + (tx << 2);
  #pragma unroll
  for (int i2 = 0; i2 < 4; ++i2) {
    float4 o4;
    o4.x = __fadd_rn(acc1[i2][0], acc2[i2][0]);
    o4.y = __fadd_rn(acc1[i2][1], acc2[i2][1]);
    o4.z = __fadd_rn(acc1[i2][2], acc2[i2][2]);
    o4.w = __fadd_rn(acc1[i2][3], acc2[i2][3]);
    *(float4*)(Cp + (size_t)i2 * N) = o4;
  }
}

__global__ __launch_bounds__(256) void rope_reshape_kernel(const float* __restrict__ raw,
    const float* __restrict__ cosT, const float* __restrict__ sinT,
    float* __restrict__ qb, float* __restrict__ kb, float* __restrict__ vb) {
  int idx = blockIdx.x * 256 + threadIdx.x;
  int s = idx >> 10;
  int n = idx & 1023;
  float val = raw[idx];
  int d = n & 63;
  if (n < 768) {
    int dp = d & 31;
    float cs = cosT[(s << 5) + dp];
    float sn = sinT[(s << 5) + dp];
    int npart = (n - d) + ((d < 32) ? d + 32 : d - 32);
    float partner = raw[(s << 10) + npart];
    float rot = (d < 32) ? -partner : partner;
    float out = __fadd_rn(__fmul_rn(val, cs), __fmul_rn(rot, sn));
    if (n < 512) {
      int h = n >> 6;
      qb[((size_t)(h * 4096 + s) << 6) + d] = out;
    } else {
      int kvh = (n - 512) >> 6;
      kb[((size_t)(kvh * 4096 + s) << 6) + d] = out;
    }
  } else {
    int kvh = (n - 768) >> 6;
    vb[((size_t)(kvh * 4096 + s) << 6) + d] = val;
  }
}

// k1[kvh][r][d] = seq-sum_c k[kvh][r*64+c][d]      (d 0..31)
// k2[kvh][c][d] = seq-sum_r k[kvh][r*64+c][d+32]
__global__ __launch_bounds__(256) void k12_np_kernel(const float* __restrict__ kb,
    float* __restrict__ k1t, float* __restrict__ k2t) {
  int id = blockIdx.x * 256 + threadIdx.x;    // 0..16383
  int which = id >> 13;
  int rem = id & 8191;
  int kvh = rem >> 11;
  int rem2 = rem & 2047;
  int i = rem2 >> 5;
  int d = rem2 & 31;
  const float* base = kb + ((size_t)(kvh * 4096) << 6);
  if (which == 0) {
    float acc = base[((size_t)(i * 64) << 6) + d];
    for (int c = 1; c < 64; ++c)
      acc = __fadd_rn(acc, base[((size_t)(i * 64 + c) << 6) + d]);
    k1t[(kvh * 64 + i) * 32 + d] = acc;
  } else {
    float acc = base[((size_t)i << 6) + d + 32];
    for (int r = 1; r < 64; ++r)
      acc = __fadd_rn(acc, base[((size_t)(r * 64 + i) << 6) + d + 32]);
    k2t[(kvh * 64 + i) * 32 + d] = acc;
  }
}

// Wave-parallel attention: one wave per (h,s), numpy-f32-faithful per output.
__global__ __launch_bounds__(256) void attn_wave_kernel(const float* __restrict__ qb,
    const float* __restrict__ vb, const float* __restrict__ k1t,
    const float* __restrict__ k2t, float* __restrict__ ob) {
  __shared__ float lk1[64 * LKP];   // [r][d], stride-33 padded
  __shared__ float lk2[64 * LKP];
  const int lane = threadIdx.x & 63;
  const int w = blockIdx.x * 4 + (threadIdx.x >> 6);
  const int h = w >> 12;            // 4 waves/block share h (4096 s per h)
  const int s = w & 4095;
  const int kvh = h >> 1;
  for (int j = threadIdx.x; j < 2048; j += 256) {
    int r = j >> 5, d = j & 31;
    lk1[r * LKP + d] = k1t[kvh * 2048 + j];
    lk2[r * LKP + d] = k2t[kvh * 2048 + j];
  }
  __syncthreads();

  const float qv = qb[((size_t)(h * 4096 + s) << 6) + lane];  // lane d holds q[d]

  // stage-1: lane r computes s1,s2 as fmaf chains in d-order
  float s1 = 0.f, s2 = 0.f;
  #pragma unroll
  for (int d = 0; d < 32; ++d) {
    float q1 = __shfl(qv, d, 64);
    float q2 = __shfl(qv, d + 32, 64);
    s1 = fmaf(q1, lk1[lane * LKP + d], s1);
    s2 = fmaf(q2, lk2[lane * LKP + d], s2);
  }
  // top-8 (desc, ties->lower index); lane it holds it-th result
  float t1v = 0.f, t2v = 0.f;
  int t1i = 0, t2i = 0;
  {
    float cur = s1;
    #pragma unroll
    for (int it = 0; it < 8; ++it) {
      float mv = cur; int mi = lane;
      #pragma unroll
      for (int off = 32; off; off >>= 1) {
        float ov = __shfl_xor(mv, off, 64);
        int oi = __shfl_xor(mi, off, 64);
        if (ov > mv || (ov == mv && oi < mi)) { mv = ov; mi = oi; }
      }
      if (lane == it) { t1v = mv; t1i = mi; }
      if (lane == mi) cur = -INFINITY;
    }
  }
  {
    float cur = s2;
    #pragma unroll
    for (int it = 0; it < 8; ++it) {
      float mv = cur; int mi = lane;
      #pragma unroll
      for (int off = 32; off; off >>= 1) {
        float ov = __shfl_xor(mv, off, 64);
        int oi = __shfl_xor(mi, off, 64);
        if (ov > mv || (ov == mv && oi < mi)) { mv = ov; mi = oi; }
      }
      if (lane == it) { t2v = mv; t2i = mi; }
      if (lane == mi) cur = -INFINITY;
    }
  }
  // stage-2: lane c computes candidate score as mul+add chain over d=0..63
  int r1 = __shfl(t1i, lane >> 3, 64);
  int r2 = __shfl(t2i, lane & 7, 64);
  float sc = 0.f;
  #pragma unroll
  for (int d = 0; d < 32; ++d) {
    float q1 = __shfl(qv, d, 64);
    sc = __fadd_rn(sc, __fmul_rn(q1, lk1[r1 * LKP + d]));
  }
  #pragma unroll
  for (int d = 0; d < 32; ++d) {
    float q2 = __shfl(qv, d + 32, 64);
    sc = __fadd_rn(sc, __fmul_rn(q2, lk2[r2 * LKP + d]));
  }
  // top-8 of candidates
  float selv = 0.f; int selc = 0;
  {
    float cur = sc;
    #pragma unroll
    for (int it = 0; it < 8; ++it) {
      float mv = cur; int mi = lane;
      #pragma unroll
      for (int off = 32; off; off >>= 1) {
        float ov = __shfl_xor(mv, off, 64);
        int oi = __shfl_xor(mi, off, 64);
        if (ov > mv || (ov == mv && oi < mi)) { mv = ov; mi = oi; }
      }
      if (lane == it) { selv = mv; selc = mi; }
      if (lane == mi) cur = -INFINITY;
    }
  }
  float cvs[8]; int ccs[8];
  #pragma unroll
  for (int t = 0; t < 8; ++t) {
    cvs[t] = __shfl(selv, t, 64);
    ccs[t] = __shfl(selc, t, 64);
  }
  // softmax, numpy-style
  float y[8];
  #pragma unroll
  for (int t = 0; t < 8; ++t) y[t] = cvs[t] * 0.125f;   // exact pow2 scale
  float mx = y[0];
  #pragma unroll
  for (int t = 1; t < 8; ++t) if (y[t] > mx) mx = y[t];
  float e[8];
  #pragma unroll
  for (int t = 0; t < 8; ++t)
    e[t] = (float)exp((double)__fsub_rn(y[t], mx));
  float wsum = __fadd_rn(__fadd_rn(__fadd_rn(e[0], e[1]), __fadd_rn(e[2], e[3])),
                         __fadd_rn(__fadd_rn(e[4], e[5]), __fadd_rn(e[6], e[7])));
  // o[d] = seq mul+add over t of att[t]*v_row[t][d]; lane d holds o[d]
  const float* vbh = vb + ((size_t)(kvh * 4096) << 6);
  float o = 0.f;
  #pragma unroll
  for (int t = 0; t < 8; ++t) {
    float att = __fdiv_rn(e[t], wsum);
    int cc = ccs[t];
    int row = __shfl(t1i, cc >> 3, 64);
    int col = __shfl(t2i, cc & 7, 64);
    o = __fadd_rn(o, __fmul_rn(att, vbh[((size_t)(row * 64 + col) << 6) + lane]));
  }
  ob[(size_t)s * 512 + (h << 6) + lane] = o;
}

extern "C" void kernel_launch(void* const* d_in, const int* in_sizes, int n_in,
                              void* d_out, int out_size, void* d_ws, size_t ws_size,
                              hipStream_t stream) {
  const float* x  = (const float*)d_in[0];
  const float* Wq = (const float*)d_in[1];
  const float* Wk = (const float*)d_in[2];
  const float* Wv = (const float*)d_in[3];
  const float* Wo = (const float*)d_in[4];
  float* ws = (float*)d_ws;
  float* qkv  = ws + OFF_QKV;
  float* qb   = ws + OFF_Q;
  float* kb   = ws + OFF_K;
  float* vb   = ws + OFF_V;
  float* cosT = ws + OFF_COS;
  float* sinT = ws + OFF_SIN;
  float* k1t  = ws + OFF_K1;
  float* k2t  = ws + OFF_K2;
  float* ob   = ws + OFF_O;
  float* wcat = ws + OFF_W;

  hipMemcpyAsync(wcat,             Wq, (size_t)512 * 512 * sizeof(float), hipMemcpyDeviceToDevice, stream);
  hipMemcpyAsync(wcat + 512 * 512, Wk, (size_t)256 * 512 * sizeof(float), hipMemcpyDeviceToDevice, stream);
  hipMemcpyAsync(wcat + 768 * 512, Wv, (size_t)256 * 512 * sizeof(float), hipMemcpyDeviceToDevice, stream);

  freq_table_kernel<<<512, 256, 0, stream>>>(cosT, sinT);
  gemm_nt_chain<384><<<dim3(1024 / 64, 4096 / 64), 256, 0, stream>>>(x, wcat, qkv, 1024);
  rope_reshape_kernel<<<16384, 256, 0, stream>>>(qkv, cosT, sinT, qb, kb, vb);
  k12_np_kernel<<<64, 256, 0, stream>>>(kb, k1t, k2t);
  attn_wave_kernel<<<8192, 256, 0, stream>>>(qb, vb, k1t, k2t, ob);
  gemm_nt_chain<0><<<dim3(512 / 64, 4096 / 64), 256, 0, stream>>>(ob, Wo, (float*)d_out, 512);
}

// Round 8
// 263.519 us; speedup vs baseline: 1.3521x; 1.3521x over previous
//
#include <hip/hip_runtime.h>
#include <math.h>

// Problem: S=4096, D=512, H=8, KVH=4, DH=64, M=64, K=8 (B=1)
// ARITHMETIC CONTRACT (frozen, round 5 green): selection-critical path
// emulates numpy-f32 op-for-op:
//  - QKV gemm: per output, sequential f32 fmaf chain in k-ascending order,
//    KC=384 panel split, final __fadd_rn(acc1, acc2)
//  - k1/k2 sums: sequential f32 adds in axis order
//  - stage-1 scores: sequential fmaf chain over d (0..31)
//  - stage-2 einsum: sequential f32 mul+add (NOT fma) over d (0..63)
//  - tables: correctly-rounded f32 (f64 then round)
//  - top-k: descending, ties -> lower index (bitonic w/ total order == argmax iter)
//  - softmax: *0.125, expf (value-path only), pairwise-8 sum, f32 div
// Round 7: bitonic sorts, LDS-b128 q broadcasts, __expf, readlane epilogue.

// Workspace (floats)
static constexpr size_t OFF_QKV = 0;              // 4096*1024
static constexpr size_t OFF_Q   = 4194304;        // 8*4096*64   q[h][s][d]
static constexpr size_t OFF_K   = 6291456;        // 4*4096*64   k[kvh][s][d]
static constexpr size_t OFF_V   = 7340032;        // 4*4096*64   v[kvh][s][d]
static constexpr size_t OFF_COS = 8388608;        // 4096*32
static constexpr size_t OFF_SIN = 8519680;        // 4096*32
static constexpr size_t OFF_K1  = 8650752;        // 4*64*32     k1[kvh][r][d]
static constexpr size_t OFF_K2  = 8658944;        // 4*64*32     k2[kvh][c][d]
static constexpr size_t OFF_O   = 8667136;        // 4096*512
static constexpr size_t OFF_W   = 10764288;       // 1024*512

#define LDT 68   // GEMM LDS pad
#define LKP 33   // attn k-row LDS pad: bank (r+d)%32, 2-way (free)

__device__ __forceinline__ float rdlane_f(float v, int lane) {
  return __int_as_float(__builtin_amdgcn_readlane(__float_as_int(v), lane));
}
__device__ __forceinline__ int rdlane_i(int v, int lane) {
  return __builtin_amdgcn_readlane(v, lane);
}

__global__ __launch_bounds__(256) void freq_table_kernel(float* __restrict__ cosT,
    float* __restrict__ sinT) {
  int idx = blockIdx.x * 256 + threadIdx.x;   // 0..131071
  int s = idx >> 5;
  int dp = idx & 31;
  double e = (double)dp * (1.0 / 32.0);
  float pf = (float)pow(10000.0, e);
  float invf = 1.0f / pf;
  float argf = __fmul_rn((float)s, invf);
  cosT[idx] = (float)cos((double)argf);
  sinT[idx] = (float)sin((double)argf);
}

// Tiled NT gemm, chain-order-preserving, KC split via template.
template <int SPLIT>
__global__ __launch_bounds__(256) void gemm_nt_chain(const float* __restrict__ A,
    const float* __restrict__ B, float* __restrict__ C, int N) {
  __shared__ float As[16 * LDT];
  __shared__ float Bs[16 * LDT];
  const int tid = threadIdx.x;
  const int ty = tid >> 4;
  const int tx = tid & 15;
  const int bm = blockIdx.y, bn = blockIdx.x;
  const int lrow = tid >> 2;
  const int lk = (tid & 3) << 2;
  const float* Ap = A + (size_t)(bm * 64 + lrow) * 512 + lk;
  const float* Bp = B + (size_t)(bn * 64 + lrow) * 512 + lk;
  float acc1[4][4] = {{0.f}};
  float acc2[4][4] = {{0.f}};
  for (int kt = 0; kt < 512; kt += 16) {
    float4 av = *(const float4*)(Ap + kt);
    float4 bv = *(const float4*)(Bp + kt);
    __syncthreads();
    As[(lk + 0) * LDT + lrow] = av.x;
    As[(lk + 1) * LDT + lrow] = av.y;
    As[(lk + 2) * LDT + lrow] = av.z;
    As[(lk + 3) * LDT + lrow] = av.w;
    Bs[(lk + 0) * LDT + lrow] = bv.x;
    Bs[(lk + 1) * LDT + lrow] = bv.y;
    Bs[(lk + 2) * LDT + lrow] = bv.z;
    Bs[(lk + 3) * LDT + lrow] = bv.w;
    __syncthreads();
    if (SPLIT != 0 && kt >= SPLIT) {
      #pragma unroll
      for (int k = 0; k < 16; ++k) {
        float4 a4 = *(const float4*)(&As[k * LDT + (ty << 2)]);
        float4 b4 = *(const float4*)(&Bs[k * LDT + (tx << 2)]);
        float af[4] = {a4.x, a4.y, a4.z, a4.w};
        float bf[4] = {b4.x, b4.y, b4.z, b4.w};
        #pragma unroll
        for (int i2 = 0; i2 < 4; ++i2)
          #pragma unroll
          for (int j2 = 0; j2 < 4; ++j2)
            acc2[i2][j2] = fmaf(af[i2], bf[j2], acc2[i2][j2]);
      }
    } else {
      #pragma unroll
      for (int k = 0; k < 16; ++k) {
        float4 a4 = *(const float4*)(&As[k * LDT + (ty << 2)]);
        float4 b4 = *(const float4*)(&Bs[k * LDT + (tx << 2)]);
        float af[4] = {a4.x, a4.y, a4.z, a4.w};
        float bf[4] = {b4.x, b4.y, b4.z, b4.w};
        #pragma unroll
        for (int i2 = 0; i2 < 4; ++i2)
          #pragma unroll
          for (int j2 = 0; j2 < 4; ++j2)
            acc1[i2][j2] = fmaf(af[i2], bf[j2], acc1[i2][j2]);
      }
    }
  }
  float* Cp = C + (size_t)(bm * 64 + (ty << 2)) * N + bn * 64 + (tx << 2);
  #pragma unroll
  for (int i2 = 0; i2 < 4; ++i2) {
    float4 o4;
    o4.x = __fadd_rn(acc1[i2][0], acc2[i2][0]);
    o4.y = __fadd_rn(acc1[i2][1], acc2[i2][1]);
    o4.z = __fadd_rn(acc1[i2][2], acc2[i2][2]);
    o4.w = __fadd_rn(acc1[i2][3], acc2[i2][3]);
    *(float4*)(Cp + (size_t)i2 * N) = o4;
  }
}

__global__ __launch_bounds__(256) void rope_reshape_kernel(const float* __restrict__ raw,
    const float* __restrict__ cosT, const float* __restrict__ sinT,
    float* __restrict__ qb, float* __restrict__ kb, float* __restrict__ vb) {
  int idx = blockIdx.x * 256 + threadIdx.x;
  int s = idx >> 10;
  int n = idx & 1023;
  float val = raw[idx];
  int d = n & 63;
  if (n < 768) {
    int dp = d & 31;
    float cs = cosT[(s << 5) + dp];
    float sn = sinT[(s << 5) + dp];
    int npart = (n - d) + ((d < 32) ? d + 32 : d - 32);
    float partner = raw[(s << 10) + npart];
    float rot = (d < 32) ? -partner : partner;
    float out = __fadd_rn(__fmul_rn(val, cs), __fmul_rn(rot, sn));
    if (n < 512) {
      int h = n >> 6;
      qb[((size_t)(h * 4096 + s) << 6) + d] = out;
    } else {
      int kvh = (n - 512) >> 6;
      kb[((size_t)(kvh * 4096 + s) << 6) + d] = out;
    }
  } else {
    int kvh = (n - 768) >> 6;
    vb[((size_t)(kvh * 4096 + s) << 6) + d] = val;
  }
}

__global__ __launch_bounds__(256) void k12_np_kernel(const float* __restrict__ kb,
    float* __restrict__ k1t, float* __restrict__ k2t) {
  int id = blockIdx.x * 256 + threadIdx.x;    // 0..16383
  int which = id >> 13;
  int rem = id & 8191;
  int kvh = rem >> 11;
  int rem2 = rem & 2047;
  int i = rem2 >> 5;
  int d = rem2 & 31;
  const float* base = kb + ((size_t)(kvh * 4096) << 6);
  if (which == 0) {
    float acc = base[((size_t)(i * 64) << 6) + d];
    for (int c = 1; c < 64; ++c)
      acc = __fadd_rn(acc, base[((size_t)(i * 64 + c) << 6) + d]);
    k1t[(kvh * 64 + i) * 32 + d] = acc;
  } else {
    float acc = base[((size_t)i << 6) + d + 32];
    for (int r = 1; r < 64; ++r)
      acc = __fadd_rn(acc, base[((size_t)(r * 64 + i) << 6) + d + 32]);
    k2t[(kvh * 64 + i) * 32 + d] = acc;
  }
}

// Full bitonic sort of 64 (val,idx) pairs, descending by (val desc, idx asc).
// Valid total order => sorted prefix == iterative argmax w/ lower-index ties.
__device__ __forceinline__ void bitonic64_desc(float& v, int& idx, int lane) {
  #pragma unroll
  for (int k = 2; k <= 64; k <<= 1) {
    #pragma unroll
    for (int j = k >> 1; j >= 1; j >>= 1) {
      float ov = __shfl_xor(v, j, 64);
      int   oi = __shfl_xor(idx, j, 64);
      bool othergreater = (ov > v) || (ov == v && oi < idx);
      bool lower = ((lane & j) == 0);
      bool desc = ((lane & k) == 0);
      bool take = ((desc == lower) == othergreater);
      v = take ? ov : v;
      idx = take ? oi : idx;
    }
  }
}

// Wave-parallel attention v2: one wave per (h,s).
__global__ __launch_bounds__(256) void attn_wave_kernel(const float* __restrict__ qb,
    const float* __restrict__ vb, const float* __restrict__ k1t,
    const float* __restrict__ k2t, float* __restrict__ ob) {
  __shared__ float lk1[64 * LKP];
  __shared__ float lk2[64 * LKP];
  __shared__ __align__(16) float wq[4 * 64];   // per-wave q staging
  const int lane = threadIdx.x & 63;
  const int wv = threadIdx.x >> 6;
  const int w = blockIdx.x * 4 + wv;
  const int h = w >> 12;
  const int s = w & 4095;
  const int kvh = h >> 1;
  for (int j = threadIdx.x; j < 2048; j += 256) {
    int r = j >> 5, d = j & 31;
    lk1[r * LKP + d] = k1t[kvh * 2048 + j];
    lk2[r * LKP + d] = k2t[kvh * 2048 + j];
  }
  __syncthreads();

  const float qv = qb[((size_t)(h * 4096 + s) << 6) + lane];
  wq[(wv << 6) + lane] = qv;          // same-wave write->read, hw-ordered

  // stage-1: lane r computes s1,s2 as fmaf chains in d-ascending order
  float s1 = 0.f, s2 = 0.f;
  const float* k1r = &lk1[lane * LKP];
  const float* k2r = &lk2[lane * LKP];
  #pragma unroll
  for (int dq = 0; dq < 32; dq += 4) {
    float4 q1 = *(const float4*)&wq[(wv << 6) + dq];        // broadcast b128
    float4 q2 = *(const float4*)&wq[(wv << 6) + 32 + dq];
    s1 = fmaf(q1.x, k1r[dq + 0], s1);
    s1 = fmaf(q1.y, k1r[dq + 1], s1);
    s1 = fmaf(q1.z, k1r[dq + 2], s1);
    s1 = fmaf(q1.w, k1r[dq + 3], s1);
    s2 = fmaf(q2.x, k2r[dq + 0], s2);
    s2 = fmaf(q2.y, k2r[dq + 1], s2);
    s2 = fmaf(q2.z, k2r[dq + 2], s2);
    s2 = fmaf(q2.w, k2r[dq + 3], s2);
  }
  // sort both score sets; lane t<8 holds t-th (desc)
  float v1 = s1, v2 = s2;
  int i1 = lane, i2 = lane;
  bitonic64_desc(v1, i1, lane);
  bitonic64_desc(v2, i2, lane);

  // stage-2: lane c (candidate c = it1*8 + it2): mul+add chain over d=0..63
  int r1 = __shfl(i1, lane >> 3, 64);
  int r2 = __shfl(i2, lane & 7, 64);
  const float* kr1 = &lk1[r1 * LKP];
  const float* kr2 = &lk2[r2 * LKP];
  float sc = 0.f;
  #pragma unroll
  for (int dq = 0; dq < 32; dq += 4) {
    float4 q1 = *(const float4*)&wq[(wv << 6) + dq];
    sc = __fadd_rn(sc, __fmul_rn(q1.x, kr1[dq + 0]));
    sc = __fadd_rn(sc, __fmul_rn(q1.y, kr1[dq + 1]));
    sc = __fadd_rn(sc, __fmul_rn(q1.z, kr1[dq + 2]));
    sc = __fadd_rn(sc, __fmul_rn(q1.w, kr1[dq + 3]));
  }
  #pragma unroll
  for (int dq = 0; dq < 32; dq += 4) {
    float4 q2 = *(const float4*)&wq[(wv << 6) + 32 + dq];
    sc = __fadd_rn(sc, __fmul_rn(q2.x, kr2[dq + 0]));
    sc = __fadd_rn(sc, __fmul_rn(q2.y, kr2[dq + 1]));
    sc = __fadd_rn(sc, __fmul_rn(q2.z, kr2[dq + 2]));
    sc = __fadd_rn(sc, __fmul_rn(q2.w, kr2[dq + 3]));
  }
  // sort candidates
  float v3 = sc;
  int i3 = lane;
  bitonic64_desc(v3, i3, lane);

  // epilogue: broadcast top-8 via readlane (uniform)
  float y[8];
  int cc[8];
  #pragma unroll
  for (int t = 0; t < 8; ++t) {
    y[t] = rdlane_f(v3, t) * 0.125f;    // exact pow2 scale
    cc[t] = rdlane_i(i3, t);
  }
  float mx = y[0];
  #pragma unroll
  for (int t = 1; t < 8; ++t) if (y[t] > mx) mx = y[t];
  float e[8];
  #pragma unroll
  for (int t = 0; t < 8; ++t) e[t] = __expf(__fsub_rn(y[t], mx));  // value-path only
  float wsum = __fadd_rn(__fadd_rn(__fadd_rn(e[0], e[1]), __fadd_rn(e[2], e[3])),
                         __fadd_rn(__fadd_rn(e[4], e[5]), __fadd_rn(e[6], e[7])));
  const float* vbh = vb + ((size_t)(kvh * 4096) << 6);
  float o = 0.f;
  #pragma unroll
  for (int t = 0; t < 8; ++t) {
    float att = __fdiv_rn(e[t], wsum);
    int row = rdlane_i(i1, cc[t] >> 3);   // uniform lane idx (SGPR)
    int col = rdlane_i(i2, cc[t] & 7);
    o = __fadd_rn(o, __fmul_rn(att, vbh[((size_t)(row * 64 + col) << 6) + lane]));
  }
  ob[(size_t)s * 512 + (h << 6) + lane] = o;
}

extern "C" void kernel_launch(void* const* d_in, const int* in_sizes, int n_in,
                              void* d_out, int out_size, void* d_ws, size_t ws_size,
                              hipStream_t stream) {
  const float* x  = (const float*)d_in[0];
  const float* Wq = (const float*)d_in[1];
  const float* Wk = (const float*)d_in[2];
  const float* Wv = (const float*)d_in[3];
  const float* Wo = (const float*)d_in[4];
  float* ws = (float*)d_ws;
  float* qkv  = ws + OFF_QKV;
  float* qb   = ws + OFF_Q;
  float* kb   = ws + OFF_K;
  float* vb   = ws + OFF_V;
  float* cosT = ws + OFF_COS;
  float* sinT = ws + OFF_SIN;
  float* k1t  = ws + OFF_K1;
  float* k2t  = ws + OFF_K2;
  float* ob   = ws + OFF_O;
  float* wcat = ws + OFF_W;

  hipMemcpyAsync(wcat,             Wq, (size_t)512 * 512 * sizeof(float), hipMemcpyDeviceToDevice, stream);
  hipMemcpyAsync(wcat + 512 * 512, Wk, (size_t)256 * 512 * sizeof(float), hipMemcpyDeviceToDevice, stream);
  hipMemcpyAsync(wcat + 768 * 512, Wv, (size_t)256 * 512 * sizeof(float), hipMemcpyDeviceToDevice, stream);

  freq_table_kernel<<<512, 256, 0, stream>>>(cosT, sinT);
  gemm_nt_chain<384><<<dim3(1024 / 64, 4096 / 64), 256, 0, stream>>>(x, wcat, qkv, 1024);
  rope_reshape_kernel<<<16384, 256, 0, stream>>>(qkv, cosT, sinT, qb, kb, vb);
  k12_np_kernel<<<64, 256, 0, stream>>>(kb, k1t, k2t);
  attn_wave_kernel<<<8192, 256, 0, stream>>>(qb, vb, k1t, k2t, ob);
  gemm_nt_chain<0><<<dim3(512 / 64, 4096 / 64), 256, 0, stream>>>(ob, Wo, (float*)d_out, 512);
}

// Round 9
// 246.605 us; speedup vs baseline: 1.4448x; 1.0686x over previous
//
#include <hip/hip_runtime.h>
#include <math.h>

// Problem: S=4096, D=512, H=8, KVH=4, DH=64, M=64, K=8 (B=1)
// ARITHMETIC CONTRACT (frozen, round 5 green): selection-critical path
// emulates numpy-f32 op-for-op:
//  - QKV gemm: per output, sequential f32 fmaf chain in k-ascending order,
//    KC=384 panel split, final __fadd_rn(acc1, acc2)
//  - k1/k2 sums: sequential f32 adds in axis order
//  - stage-1 scores: sequential fmaf chain over d (0..31)   [now in GEMM]
//  - stage-2 einsum: sequential f32 mul+add (NOT fma) over d (0..63)
//  - tables: correctly-rounded f32 (f64 then round)  [do NOT touch]
//  - top-k: descending, ties -> lower index
//  - softmax: *0.125, __expf (value-path), pairwise-8 sum, f32 div
// Round 8: stage-1 -> tiled GEMM; values-only bitonic + ballot recovery;
// attention kernel uses NO LDS data (k-rows via vmem, q via readlane).

// Workspace (floats)
static constexpr size_t OFF_QKV = 0;              // 4096*1024 (reused as scores)
static constexpr size_t OFF_Q   = 4194304;        // 8*4096*64   q[h][s][d]
static constexpr size_t OFF_K   = 6291456;        // 4*4096*64   k[kvh][s][d]
static constexpr size_t OFF_V   = 7340032;        // 4*4096*64   v[kvh][s][d]
static constexpr size_t OFF_COS = 8388608;        // 4096*32
static constexpr size_t OFF_SIN = 8519680;        // 4096*32
static constexpr size_t OFF_K1  = 8650752;        // 4*64*32     k1[kvh][r][d]
static constexpr size_t OFF_K2  = 8658944;        // 4*64*32     k2[kvh][c][d]
static constexpr size_t OFF_O   = 8667136;        // 4096*512
static constexpr size_t OFF_W   = 10764288;       // 1024*512

#define LDT 68   // GEMM LDS pad

__device__ __forceinline__ float rdlane_f(float v, int lane) {
  return __int_as_float(__builtin_amdgcn_readlane(__float_as_int(v), lane));
}

__global__ __launch_bounds__(256) void freq_table_kernel(float* __restrict__ cosT,
    float* __restrict__ sinT) {
  int idx = blockIdx.x * 256 + threadIdx.x;   // 0..131071
  int s = idx >> 5;
  int dp = idx & 31;
  double e = (double)dp * (1.0 / 32.0);
  float pf = (float)pow(10000.0, e);
  float invf = 1.0f / pf;
  float argf = __fmul_rn((float)s, invf);
  cosT[idx] = (float)cos((double)argf);
  sinT[idx] = (float)sin((double)argf);
}

// Tiled NT gemm, chain-order-preserving, KC split via template.
template <int SPLIT>
__global__ __launch_bounds__(256) void gemm_nt_chain(const float* __restrict__ A,
    const float* __restrict__ B, float* __restrict__ C, int N) {
  __shared__ float As[16 * LDT];
  __shared__ float Bs[16 * LDT];
  const int tid = threadIdx.x;
  const int ty = tid >> 4;
  const int tx = tid & 15;
  const int bm = blockIdx.y, bn = blockIdx.x;
  const int lrow = tid >> 2;
  const int lk = (tid & 3) << 2;
  const float* Ap = A + (size_t)(bm * 64 + lrow) * 512 + lk;
  const float* Bp = B + (size_t)(bn * 64 + lrow) * 512 + lk;
  float acc1[4][4] = {{0.f}};
  float acc2[4][4] = {{0.f}};
  for (int kt = 0; kt < 512; kt += 16) {
    float4 av = *(const float4*)(Ap + kt);
    float4 bv = *(const float4*)(Bp + kt);
    __syncthreads();
    As[(lk + 0) * LDT + lrow] = av.x;
    As[(lk + 1) * LDT + lrow] = av.y;
    As[(lk + 2) * LDT + lrow] = av.z;
    As[(lk + 3) * LDT + lrow] = av.w;
    Bs[(lk + 0) * LDT + lrow] = bv.x;
    Bs[(lk + 1) * LDT + lrow] = bv.y;
    Bs[(lk + 2) * LDT + lrow] = bv.z;
    Bs[(lk + 3) * LDT + lrow] = bv.w;
    __syncthreads();
    if (SPLIT != 0 && kt >= SPLIT) {
      #pragma unroll
      for (int k = 0; k < 16; ++k) {
        float4 a4 = *(const float4*)(&As[k * LDT + (ty << 2)]);
        float4 b4 = *(const float4*)(&Bs[k * LDT + (tx << 2)]);
        float af[4] = {a4.x, a4.y, a4.z, a4.w};
        float bf[4] = {b4.x, b4.y, b4.z, b4.w};
        #pragma unroll
        for (int i2 = 0; i2 < 4; ++i2)
          #pragma unroll
          for (int j2 = 0; j2 < 4; ++j2)
            acc2[i2][j2] = fmaf(af[i2], bf[j2], acc2[i2][j2]);
      }
    } else {
      #pragma unroll
      for (int k = 0; k < 16; ++k) {
        float4 a4 = *(const float4*)(&As[k * LDT + (ty << 2)]);
        float4 b4 = *(const float4*)(&Bs[k * LDT + (tx << 2)]);
        float af[4] = {a4.x, a4.y, a4.z, a4.w};
        float bf[4] = {b4.x, b4.y, b4.z, b4.w};
        #pragma unroll
        for (int i2 = 0; i2 < 4; ++i2)
          #pragma unroll
          for (int j2 = 0; j2 < 4; ++j2)
            acc1[i2][j2] = fmaf(af[i2], bf[j2], acc1[i2][j2]);
      }
    }
  }
  float* Cp = C + (size_t)(bm * 64 + (ty << 2)) * N + bn * 64 + (tx << 2);
  #pragma unroll
  for (int i2 = 0; i2 < 4; ++i2) {
    float4 o4;
    o4.x = __fadd_rn(acc1[i2][0], acc2[i2][0]);
    o4.y = __fadd_rn(acc1[i2][1], acc2[i2][1]);
    o4.z = __fadd_rn(acc1[i2][2], acc2[i2][2]);
    o4.w = __fadd_rn(acc1[i2][3], acc2[i2][3]);
    *(float4*)(Cp + (size_t)i2 * N) = o4;
  }
}

__global__ __launch_bounds__(256) void rope_reshape_kernel(const float* __restrict__ raw,
    const float* __restrict__ cosT, const float* __restrict__ sinT,
    float* __restrict__ qb, float* __restrict__ kb, float* __restrict__ vb) {
  int idx = blockIdx.x * 256 + threadIdx.x;
  int s = idx >> 10;
  int n = idx & 1023;
  float val = raw[idx];
  int d = n & 63;
  if (n < 768) {
    int dp = d & 31;
    float cs = cosT[(s << 5) + dp];
    float sn = sinT[(s << 5) + dp];
    int npart = (n - d) + ((d < 32) ? d + 32 : d - 32);
    float partner = raw[(s << 10) + npart];
    float rot = (d < 32) ? -partner : partner;
    float out = __fadd_rn(__fmul_rn(val, cs), __fmul_rn(rot, sn));
    if (n < 512) {
      int h = n >> 6;
      qb[((size_t)(h * 4096 + s) << 6) + d] = out;
    } else {
      int kvh = (n - 512) >> 6;
      kb[((size_t)(kvh * 4096 + s) << 6) + d] = out;
    }
  } else {
    int kvh = (n - 768) >> 6;
    vb[((size_t)(kvh * 4096 + s) << 6) + d] = val;
  }
}

__global__ __launch_bounds__(256) void k12_np_kernel(const float* __restrict__ kb,
    float* __restrict__ k1t, float* __restrict__ k2t) {
  int id = blockIdx.x * 256 + threadIdx.x;    // 0..16383
  int which = id >> 13;
  int rem = id & 8191;
  int kvh = rem >> 11;
  int rem2 = rem & 2047;
  int i = rem2 >> 5;
  int d = rem2 & 31;
  const float* base = kb + ((size_t)(kvh * 4096) << 6);
  if (which == 0) {
    float acc = base[((size_t)(i * 64) << 6) + d];
    for (int c = 1; c < 64; ++c)
      acc = __fadd_rn(acc, base[((size_t)(i * 64 + c) << 6) + d]);
    k1t[(kvh * 64 + i) * 32 + d] = acc;
  } else {
    float acc = base[((size_t)i << 6) + d + 32];
    for (int r = 1; r < 64; ++r)
      acc = __fadd_rn(acc, base[((size_t)(r * 64 + i) << 6) + d + 32]);
    k2t[(kvh * 64 + i) * 32 + d] = acc;
  }
}

// Stage-1 scores as a tiled GEMM (fmaf chain over d ascending, per output —
// identical op sequence to the previous in-attn computation).
// sc[h][s][r]      = chain_d q[h][s][d]    * k1[kvh][r][d]   (r 0..63)
// sc[h][s][64+r]   = chain_d q[h][s][32+d] * k2[kvh][r][d]
__global__ __launch_bounds__(256) void stage1_scores_kernel(
    const float* __restrict__ qb, const float* __restrict__ k1t,
    const float* __restrict__ k2t, float* __restrict__ sc) {
  __shared__ float qs[64 * 68];     // [d][s]
  __shared__ float kd[32 * 132];    // [d][r2]  r2 = k1|k2
  const int t = threadIdx.x;
  const int h = blockIdx.y;
  const int s0 = blockIdx.x * 64;
  const int kvh = h >> 1;
  #pragma unroll
  for (int i = 0; i < 16; ++i) {
    int j = t + i * 256;            // 0..4095
    int ss = j >> 6, d = j & 63;
    qs[d * 68 + ss] = qb[((size_t)(h * 4096 + s0 + ss) << 6) + d];
  }
  #pragma unroll
  for (int i = 0; i < 8; ++i) {
    int j = t + i * 256;            // 0..2047
    int r = j >> 5, d = j & 31;
    kd[d * 132 + r]      = k1t[(kvh * 64 + r) * 32 + d];
    kd[d * 132 + 64 + r] = k2t[(kvh * 64 + r) * 32 + d];
  }
  __syncthreads();
  const int ty = t >> 4;            // s group (4 rows)
  const int tx = t & 15;            // col group (8 cols)
  const int qrow = (tx >= 8) ? 32 : 0;
  float acc[4][8] = {{0.f}};
  #pragma unroll
  for (int d = 0; d < 32; ++d) {
    float4 a4 = *(const float4*)&qs[(qrow + d) * 68 + (ty << 2)];
    float4 b0 = *(const float4*)&kd[d * 132 + (tx << 3)];
    float4 b1 = *(const float4*)&kd[d * 132 + (tx << 3) + 4];
    float af[4] = {a4.x, a4.y, a4.z, a4.w};
    float bf[8] = {b0.x, b0.y, b0.z, b0.w, b1.x, b1.y, b1.z, b1.w};
    #pragma unroll
    for (int i2 = 0; i2 < 4; ++i2)
      #pragma unroll
      for (int j2 = 0; j2 < 8; ++j2)
        acc[i2][j2] = fmaf(af[i2], bf[j2], acc[i2][j2]);
  }
  #pragma unroll
  for (int i2 = 0; i2 < 4; ++i2) {
    float* p = sc + (((size_t)(h * 4096 + s0 + (ty << 2) + i2)) << 7) + (tx << 3);
    *(float4*)(p)     = make_float4(acc[i2][0], acc[i2][1], acc[i2][2], acc[i2][3]);
    *(float4*)(p + 4) = make_float4(acc[i2][4], acc[i2][5], acc[i2][6], acc[i2][7]);
  }
}

// Values-only bitonic sort (descending). Ties resolve arbitrarily here;
// index semantics are restored by the ballot recovery afterwards.
__device__ __forceinline__ void bitonic64_val_desc(float& v, int lane) {
  #pragma unroll
  for (int k = 2; k <= 64; k <<= 1) {
    #pragma unroll
    for (int j = k >> 1; j >= 1; j >>= 1) {
      float ov = __shfl_xor(v, j, 64);
      bool up = ((lane & k) == 0) == ((lane & j) == 0);
      float mx = fmaxf(v, ov), mn = fminf(v, ov);
      v = up ? mx : mn;
    }
  }
}

// Selection kernel: one wave per (h,s); no LDS data at all.
__global__ __launch_bounds__(256) void attn_sel_kernel(const float* __restrict__ sc,
    const float* __restrict__ qb, const float* __restrict__ vb,
    const float* __restrict__ k1t, const float* __restrict__ k2t,
    float* __restrict__ ob) {
  const int lane = threadIdx.x & 63;
  const int w = blockIdx.x * 4 + (threadIdx.x >> 6);   // w = h*4096 + s
  const int h = w >> 12;
  const int s = w & 4095;
  const int kvh = h >> 1;
  const float* scp = sc + ((size_t)w << 7);
  const float s1 = scp[lane];
  const float s2 = scp[64 + lane];
  const float qv = qb[((size_t)w << 6) + lane];

  // top-8 of s1: sort values, recover indices (iterative-argmax semantics)
  float v1 = s1;
  bitonic64_val_desc(v1, lane);
  unsigned long long pack1 = 0, used = 0;
  #pragma unroll
  for (int t = 0; t < 8; ++t) {
    float tv = rdlane_f(v1, t);
    unsigned long long m = __ballot(s1 == tv) & ~used;
    int ix = __ffsll((long long)m) - 1;
    used |= 1ull << ix;
    pack1 |= (unsigned long long)ix << (6 * t);
  }
  float v2 = s2;
  bitonic64_val_desc(v2, lane);
  unsigned long long pack2 = 0;
  used = 0;
  #pragma unroll
  for (int t = 0; t < 8; ++t) {
    float tv = rdlane_f(v2, t);
    unsigned long long m = __ballot(s2 == tv) & ~used;
    int ix = __ffsll((long long)m) - 1;
    used |= 1ull << ix;
    pack2 |= (unsigned long long)ix << (6 * t);
  }

  // stage-2: lane c = it1*8+it2; mul+add chain over d=0..63 (non-fma)
  int r1 = (int)((pack1 >> (6 * (lane >> 3))) & 63);
  int r2 = (int)((pack2 >> (6 * (lane & 7))) & 63);
  const float* k1p = k1t + (size_t)(kvh * 64 + r1) * 32;
  const float* k2p = k2t + (size_t)(kvh * 64 + r2) * 32;
  float c = 0.f;
  #pragma unroll
  for (int dq = 0; dq < 32; dq += 4) {
    float4 kk = *(const float4*)(k1p + dq);
    c = __fadd_rn(c, __fmul_rn(rdlane_f(qv, dq + 0), kk.x));
    c = __fadd_rn(c, __fmul_rn(rdlane_f(qv, dq + 1), kk.y));
    c = __fadd_rn(c, __fmul_rn(rdlane_f(qv, dq + 2), kk.z));
    c = __fadd_rn(c, __fmul_rn(rdlane_f(qv, dq + 3), kk.w));
  }
  #pragma unroll
  for (int dq = 0; dq < 32; dq += 4) {
    float4 kk = *(const float4*)(k2p + dq);
    c = __fadd_rn(c, __fmul_rn(rdlane_f(qv, 32 + dq + 0), kk.x));
    c = __fadd_rn(c, __fmul_rn(rdlane_f(qv, 32 + dq + 1), kk.y));
    c = __fadd_rn(c, __fmul_rn(rdlane_f(qv, 32 + dq + 2), kk.z));
    c = __fadd_rn(c, __fmul_rn(rdlane_f(qv, 32 + dq + 3), kk.w));
  }
  const float scand = c;
  float v3 = c;
  bitonic64_val_desc(v3, lane);
  float cvs[8]; int ccs[8];
  used = 0;
  #pragma unroll
  for (int t = 0; t < 8; ++t) {
    float tv = rdlane_f(v3, t);
    unsigned long long m = __ballot(scand == tv) & ~used;
    int ix = __ffsll((long long)m) - 1;
    used |= 1ull << ix;
    cvs[t] = tv;
    ccs[t] = ix;
  }
  // softmax (value path)
  float y[8];
  #pragma unroll
  for (int t = 0; t < 8; ++t) y[t] = cvs[t] * 0.125f;
  float mx = y[0];
  #pragma unroll
  for (int t = 1; t < 8; ++t) if (y[t] > mx) mx = y[t];
  float e[8];
  #pragma unroll
  for (int t = 0; t < 8; ++t) e[t] = __expf(__fsub_rn(y[t], mx));
  float wsum = __fadd_rn(__fadd_rn(__fadd_rn(e[0], e[1]), __fadd_rn(e[2], e[3])),
                         __fadd_rn(__fadd_rn(e[4], e[5]), __fadd_rn(e[6], e[7])));
  const float* vbh = vb + ((size_t)kvh << 18);
  float o = 0.f;
  #pragma unroll
  for (int t = 0; t < 8; ++t) {
    float att = __fdiv_rn(e[t], wsum);
    int row = (int)((pack1 >> (6 * (ccs[t] >> 3))) & 63);
    int col = (int)((pack2 >> (6 * (ccs[t] & 7))) & 63);
    o = __fadd_rn(o, __fmul_rn(att, vbh[((size_t)(row * 64 + col) << 6) + lane]));
  }
  ob[(size_t)s * 512 + (h << 6) + lane] = o;
}

extern "C" void kernel_launch(void* const* d_in, const int* in_sizes, int n_in,
                              void* d_out, int out_size, void* d_ws, size_t ws_size,
                              hipStream_t stream) {
  const float* x  = (const float*)d_in[0];
  const float* Wq = (const float*)d_in[1];
  const float* Wk = (const float*)d_in[2];
  const float* Wv = (const float*)d_in[3];
  const float* Wo = (const float*)d_in[4];
  float* ws = (float*)d_ws;
  float* qkv  = ws + OFF_QKV;
  float* qb   = ws + OFF_Q;
  float* kb   = ws + OFF_K;
  float* vb   = ws + OFF_V;
  float* cosT = ws + OFF_COS;
  float* sinT = ws + OFF_SIN;
  float* k1t  = ws + OFF_K1;
  float* k2t  = ws + OFF_K2;
  float* ob   = ws + OFF_O;
  float* wcat = ws + OFF_W;
  float* scb  = ws + OFF_QKV;   // scores reuse the dead qkv buffer

  hipMemcpyAsync(wcat,             Wq, (size_t)512 * 512 * sizeof(float), hipMemcpyDeviceToDevice, stream);
  hipMemcpyAsync(wcat + 512 * 512, Wk, (size_t)256 * 512 * sizeof(float), hipMemcpyDeviceToDevice, stream);
  hipMemcpyAsync(wcat + 768 * 512, Wv, (size_t)256 * 512 * sizeof(float), hipMemcpyDeviceToDevice, stream);

  freq_table_kernel<<<512, 256, 0, stream>>>(cosT, sinT);
  gemm_nt_chain<384><<<dim3(1024 / 64, 4096 / 64), 256, 0, stream>>>(x, wcat, qkv, 1024);
  rope_reshape_kernel<<<16384, 256, 0, stream>>>(qkv, cosT, sinT, qb, kb, vb);
  k12_np_kernel<<<64, 256, 0, stream>>>(kb, k1t, k2t);
  stage1_scores_kernel<<<dim3(64, 8), 256, 0, stream>>>(qb, k1t, k2t, scb);
  attn_sel_kernel<<<8192, 256, 0, stream>>>(scb, qb, vb, k1t, k2t, ob);
  gemm_nt_chain<0><<<dim3(512 / 64, 4096 / 64), 256, 0, stream>>>(ob, Wo, (float*)d_out, 512);
}